// Round 2
// baseline (2371.290 us; speedup 1.0000x reference)
//
#include <hip/hip_runtime.h>
#include <stdint.h>

// Problem constants (match reference)
#define NE   64      // experts
#define HD   2048    // hidden dim
#define ND   512     // difficulty head inner dim
#define NTOK 16384   // B*S = 4*4096

typedef __attribute__((ext_vector_type(4))) float  fv4;
typedef __attribute__((ext_vector_type(8))) short  bf16x8;
typedef __attribute__((ext_vector_type(4))) float  f32x4;

// ---------- helpers ----------
__device__ inline unsigned short bf_rne(float x) {
  unsigned int u = __float_as_uint(x);
  return (unsigned short)((u + 0x7FFFu + ((u >> 16) & 1u)) >> 16);
}
__device__ inline float bf_to_f(unsigned short h) {
  return __uint_as_float((unsigned int)h << 16);
}

// ---------- K0: zero workspace ----------
__global__ void k_zero(uint4* __restrict__ p, int n16) {
  uint4 z = {0u, 0u, 0u, 0u};
  for (int i = blockIdx.x * blockDim.x + threadIdx.x; i < n16;
       i += gridDim.x * blockDim.x)
    p[i] = z;
}

// ---------- K1: gate logits, fp64 accumulation ----------
// grid (16 ksplit, 128 token-tiles), block 128 (2 waves)
// tile: 128 tokens x 64 experts, per-thread 8x8 micro-tile, K-chunk 32
// ksplit=16: 2048 blocks -> ~3 waves/SIMD (VGPR 136), vs 1 wave/SIMD at ksplit=4
#define G_KSPLIT 16
#define G_KSEG   (HD / G_KSPLIT)   // 128
#define G_KB     32
__global__ __launch_bounds__(128, 3)
void k_gate(const float* __restrict__ hs, const float* __restrict__ gw,
            double* __restrict__ lg) {
  __shared__ float sA[128 * G_KB];   // XOR-swizzled 4-float units
  __shared__ float sB[64 * G_KB];
  const int t = threadIdx.x;
  const int ksBase = blockIdx.x * G_KSEG;
  const int tokBase = blockIdx.y * 128;
  const int tx = t & 7;        // expert octet
  const int ty = t >> 3;       // token octet (0..15)

  double acc[8][8] = {};

  for (int kb = 0; kb < G_KSEG / G_KB; ++kb) {
    const int k0 = ksBase + kb * G_KB;
    // stage A: 128 rows x 32 k, units of 4 floats, swizzle key (row>>3)&7
#pragma unroll
    for (int it = 0; it < 8; ++it) {
      int idx = t + it * 128;
      int row = idx >> 3, u = idx & 7;
      fv4 v = *(const fv4*)(hs + (size_t)(tokBase + row) * HD + k0 + u * 4);
      *(fv4*)&sA[row * 32 + ((u ^ ((row >> 3) & 7)) * 4)] = v;
    }
    // stage B: 64 rows x 32 k
#pragma unroll
    for (int it = 0; it < 4; ++it) {
      int idx = t + it * 128;
      int row = idx >> 3, u = idx & 7;
      fv4 v = *(const fv4*)(gw + (size_t)row * HD + k0 + u * 4);
      *(fv4*)&sB[row * 32 + ((u ^ ((row >> 3) & 7)) * 4)] = v;
    }
    __syncthreads();
#pragma unroll
    for (int k4 = 0; k4 < 8; ++k4) {
      fv4 av[8], bv[8];
#pragma unroll
      for (int i = 0; i < 8; ++i)
        av[i] = *(const fv4*)&sA[(8 * ty + i) * 32 + ((k4 ^ (ty & 7)) * 4)];
#pragma unroll
      for (int j = 0; j < 8; ++j)
        bv[j] = *(const fv4*)&sB[(8 * tx + j) * 32 + ((k4 ^ tx) * 4)];
#pragma unroll
      for (int kk = 0; kk < 4; ++kk) {
        double ad[8], bd[8];
#pragma unroll
        for (int i = 0; i < 8; ++i) ad[i] = (double)av[i][kk];
#pragma unroll
        for (int j = 0; j < 8; ++j) bd[j] = (double)bv[j][kk];
#pragma unroll
        for (int i = 0; i < 8; ++i)
#pragma unroll
          for (int j = 0; j < 8; ++j)
            acc[i][j] = __builtin_fma(ad[i], bd[j], acc[i][j]);
      }
    }
    __syncthreads();
  }
#pragma unroll
  for (int i = 0; i < 8; ++i)
#pragma unroll
    for (int j = 0; j < 8; ++j)
      unsafeAtomicAdd(&lg[(size_t)(tokBase + 8 * ty + i) * NE + 8 * tx + j],
                      acc[i][j]);
}

// ---------- K2: difficulty head GEMM, split-bf16 3-term MFMA ----------
// grid (2 n-chunks, 128 token-tiles), block 256 (4 waves)
// tile: 128 tokens x 256 cols; wave = 64 tok x 128 cols (4x8 16x16 tiles)
// n-chunks=2 (was 8): hs logical HBM traffic 1.07GB -> 268MB
#define D_MT 128
#define D_NT 256
#define D_KB 32
__global__ __launch_bounds__(256, 2)
void k_diff(const float* __restrict__ hs, const float* __restrict__ w1,
            const float* __restrict__ b1, const float* __restrict__ w2,
            float* __restrict__ x2) {
  __shared__ unsigned short sAh[D_MT * D_KB];
  __shared__ unsigned short sAl[D_MT * D_KB];
  __shared__ unsigned short sBh[D_NT * D_KB];
  __shared__ unsigned short sBl[D_NT * D_KB];

  const int t = threadIdx.x;
  const int nBase = blockIdx.x * D_NT;
  const int tokBase = blockIdx.y * D_MT;
  const int w = t >> 6, lane = t & 63, l15 = lane & 15, q = lane >> 4;
  const int waveM = w & 1, waveN = w >> 1;

  f32x4 acc[4][8] = {};

  for (int kb = 0; kb < HD / D_KB; ++kb) {
    const int k0 = kb * D_KB;
    // stage A: 128 rows x 32 k as bf16 hi/lo; 16B units of 8 bf16,
    // swizzle key (row>>2)&3
#pragma unroll
    for (int it = 0; it < 2; ++it) {
      int idx = t + it * 256;
      int row = idx >> 2, u = idx & 3;
      const float* g = hs + (size_t)(tokBase + row) * HD + k0 + u * 8;
      fv4 v0 = *(const fv4*)g;
      fv4 v1 = *(const fv4*)(g + 4);
      union { unsigned short s[8]; uint4 v; } ph, pl;
#pragma unroll
      for (int j = 0; j < 8; ++j) {
        float x = (j < 4) ? v0[j] : v1[j - 4];
        unsigned short h = bf_rne(x);
        ph.s[j] = h;
        pl.s[j] = bf_rne(x - bf_to_f(h));
      }
      int up = u ^ ((row >> 2) & 3);
      *(uint4*)&sAh[row * 32 + up * 8] = ph.v;
      *(uint4*)&sAl[row * 32 + up * 8] = pl.v;
    }
    // stage B: 256 rows x 32 k
#pragma unroll
    for (int it = 0; it < 4; ++it) {
      int idx = t + it * 256;
      int row = idx >> 2, u = idx & 3;
      const float* g = w1 + (size_t)(nBase + row) * HD + k0 + u * 8;
      fv4 v0 = *(const fv4*)g;
      fv4 v1 = *(const fv4*)(g + 4);
      union { unsigned short s[8]; uint4 v; } ph, pl;
#pragma unroll
      for (int j = 0; j < 8; ++j) {
        float x = (j < 4) ? v0[j] : v1[j - 4];
        unsigned short h = bf_rne(x);
        ph.s[j] = h;
        pl.s[j] = bf_rne(x - bf_to_f(h));
      }
      int up = u ^ ((row >> 2) & 3);
      *(uint4*)&sBh[row * 32 + up * 8] = ph.v;
      *(uint4*)&sBl[row * 32 + up * 8] = pl.v;
    }
    __syncthreads();

    bf16x8 bh[8], bl[8];
#pragma unroll
    for (int ct = 0; ct < 8; ++ct) {
      int row = waveN * 128 + ct * 16 + l15;
      int off = row * 32 + ((q ^ ((row >> 2) & 3)) * 8);
      bh[ct] = *(const bf16x8*)&sBh[off];
      bl[ct] = *(const bf16x8*)&sBl[off];
    }
#pragma unroll
    for (int rt = 0; rt < 4; ++rt) {
      int row = waveM * 64 + rt * 16 + l15;
      int off = row * 32 + ((q ^ ((row >> 2) & 3)) * 8);
      bf16x8 ah = *(const bf16x8*)&sAh[off];
      bf16x8 al = *(const bf16x8*)&sAl[off];
#pragma unroll
      for (int ct = 0; ct < 8; ++ct) {
        acc[rt][ct] = __builtin_amdgcn_mfma_f32_16x16x32_bf16(ah, bh[ct], acc[rt][ct], 0, 0, 0);
        acc[rt][ct] = __builtin_amdgcn_mfma_f32_16x16x32_bf16(ah, bl[ct], acc[rt][ct], 0, 0, 0);
        acc[rt][ct] = __builtin_amdgcn_mfma_f32_16x16x32_bf16(al, bh[ct], acc[rt][ct], 0, 0, 0);
      }
    }
    __syncthreads();
  }

  // epilogue: x1 + b1 -> silu -> *w2 -> reduce over this wave's 128 cols
  // -> atomic into x2 (4 contributions/token: 2 col-half waves x 2 n-chunks)
  float b1v[8], w2v[8];
#pragma unroll
  for (int ct = 0; ct < 8; ++ct) {
    int c = nBase + waveN * 128 + ct * 16 + l15;
    b1v[ct] = b1[c];
    w2v[ct] = w2[c];
  }
#pragma unroll
  for (int rt = 0; rt < 4; ++rt) {
#pragma unroll
    for (int i = 0; i < 4; ++i) {
      float s = 0.f;
#pragma unroll
      for (int ct = 0; ct < 8; ++ct) {
        float x1 = acc[rt][ct][i] + b1v[ct];
        float h1 = x1 / (1.f + expf(-x1));   // silu
        s += h1 * w2v[ct];
      }
      s += __shfl_xor(s, 1, 64);
      s += __shfl_xor(s, 2, 64);
      s += __shfl_xor(s, 4, 64);
      s += __shfl_xor(s, 8, 64);
      if (l15 == 0)
        unsafeAtomicAdd(&x2[tokBase + waveM * 64 + rt * 16 + q * 4 + i], s);
    }
  }
}

// ---------- K3: per-token routing (one wave = one token's 64 experts) ----------
__global__ __launch_bounds__(256)
void k_route(const double* __restrict__ lg, const float* __restrict__ x2,
             const float* __restrict__ b2, float* __restrict__ out,
             double* __restrict__ tpe, double* __restrict__ ks_es) {
  const int t = threadIdx.x, wv = t >> 6, e = t & 63;
  const int base = blockIdx.x * 64 + wv * 16;
  const float b2v = b2[0];
  double tacc = 0.0, kacc = 0.0, eacc = 0.0;

  for (int it = 0; it < 16; ++it) {
    const int tok = base + it;
    float my = (float)lg[(size_t)tok * NE + e];
    float xv = x2[tok] + b2v;
    float d = 1.f / (1.f + expf(-xv));
    float kf = 4.f + 8.f * d;
    int ki = (int)rintf(kf);           // round-half-even, matches jnp.round
    ki = min(max(ki, 4), 12);

    int r = 0;  // stable descending rank
#pragma unroll
    for (int s = 1; s < 64; ++s) {
      int src = (e + s) & 63;
      float o = __shfl(my, src, 64);
      r += (o > my || (o == my && src < e)) ? 1 : 0;
    }
    float m = my;
#pragma unroll
    for (int off = 1; off < 64; off <<= 1) m = fmaxf(m, __shfl_xor(m, off, 64));
    float ex = (r < ki) ? expf(my - m) : 0.f;
    float sm = ex;
#pragma unroll
    for (int off = 1; off < 64; off <<= 1) sm += __shfl_xor(sm, off, 64);
    float wgt = ex / sm;
    out[(size_t)tok * NE + e] = wgt;

    tacc += (double)wgt;
    kacc += (double)kf;
    eacc += (double)(d * logf(d + 1e-8f) + (1.f - d) * logf(1.f - d + 1e-8f));
  }
  unsafeAtomicAdd(&tpe[e], tacc);
  if (e == 0) {
    unsafeAtomicAdd(&ks_es[0], kacc);
    unsafeAtomicAdd(&ks_es[1], eacc);
  }
}

// ---------- K4: aux loss ----------
__global__ void k_aux(const double* __restrict__ tpe,
                      const double* __restrict__ ks_es,
                      float* __restrict__ out) {
  const int e = threadIdx.x;  // 64 threads
  double x = tpe[e];
  double s = x;
#pragma unroll
  for (int off = 1; off < 64; off <<= 1) s += __shfl_xor(s, off, 64);
  double mean = s / 64.0;
  double dv = x - mean, v = dv * dv;
#pragma unroll
  for (int off = 1; off < 64; off <<= 1) v += __shfl_xor(v, off, 64);
  double var = v / 63.0;                       // ddof=1
  double avgk = ks_es[0] / (double)NTOK;
  double kp = 8.0 - avgk;
  kp = kp > 0.0 ? kp * kp : 0.0;               // relu(BASE_K-avg_k)^2
  double bal = var / (mean + 1e-8);
  double aux = 0.01 * (kp + bal) + 0.001 * (ks_es[1] / (double)NTOK);
  if (e == 0) out[(size_t)NTOK * NE] = (float)aux;
}

// ---------- launch ----------
extern "C" void kernel_launch(void* const* d_in, const int* in_sizes, int n_in,
                              void* d_out, int out_size, void* d_ws, size_t ws_size,
                              hipStream_t stream) {
  const float* hs = (const float*)d_in[0];
  const float* gw = (const float*)d_in[1];
  const float* w1 = (const float*)d_in[2];
  const float* b1 = (const float*)d_in[3];
  const float* w2 = (const float*)d_in[4];
  const float* b2 = (const float*)d_in[5];
  float* out = (float*)d_out;

  // workspace layout (needs ~8.07 MB)
  char* ws = (char*)d_ws;
  double* lg   = (double*)ws;               // 16384*64*8 = 8,388,608
  float*  x2   = (float*)(ws + 8388608);    // 16384*4    = 65,536
  double* tpe  = (double*)(ws + 8454144);   // 64*8       = 512
  double* ks_es = (double*)(ws + 8454656);  // 2*8        = 16

  const int n16 = 8454672 / 16;
  k_zero<<<1040, 256, 0, stream>>>((uint4*)d_ws, n16);
  k_gate<<<dim3(G_KSPLIT, NTOK / 128), 128, 0, stream>>>(hs, gw, lg);
  k_diff<<<dim3(ND / D_NT, NTOK / D_MT), 256, 0, stream>>>(hs, w1, b1, w2, x2);
  k_route<<<NTOK / 64, 256, 0, stream>>>(lg, x2, b2, out, tpe, ks_es);
  k_aux<<<1, 64, 0, stream>>>(tpe, ks_es, out);
}

// Round 3
// 1245.353 us; speedup vs baseline: 1.9041x; 1.9041x over previous
//
#include <hip/hip_runtime.h>
#include <stdint.h>

// Problem constants (match reference)
#define NE   64      // experts
#define HD   2048    // hidden dim
#define ND   512     // difficulty head inner dim
#define NTOK 16384   // B*S = 4*4096

typedef __attribute__((ext_vector_type(4))) float  fv4;
typedef __attribute__((ext_vector_type(8))) short  bf16x8;
typedef __attribute__((ext_vector_type(4))) float  f32x4;

// ---------- helpers ----------
__device__ inline unsigned short bf_rne(float x) {
  unsigned int u = __float_as_uint(x);
  return (unsigned short)((u + 0x7FFFu + ((u >> 16) & 1u)) >> 16);
}
__device__ inline float bf_to_f(unsigned short h) {
  return __uint_as_float((unsigned int)h << 16);
}

// ---------- K0: zero workspace ----------
__global__ void k_zero(uint4* __restrict__ p, int n16) {
  uint4 z = {0u, 0u, 0u, 0u};
  for (int i = blockIdx.x * blockDim.x + threadIdx.x; i < n16;
       i += gridDim.x * blockDim.x)
    p[i] = z;
}

// ---------- K1: gate logits, fp64 accumulation ----------
// grid (16 ksplit, 128 token-tiles), block 128 (2 waves)
// tile: 128 tokens x 64 experts, per-thread 8x8 micro-tile, K-chunk 32
// NOTE: launch_bounds MUST stay (128,1). acc[8][8] fp64 = 128 VGPRs live;
// (128,3) in round 2 forced VGPR 136->84 and spilled the accumulator to
// scratch (WRITE_SIZE 131MB->3.25GB, 5.5x regression). Occupancy comes from
// the 2048-block grid: VGPR 136 naturally allows 3 waves/EU.
#define G_KSPLIT 16
#define G_KSEG   (HD / G_KSPLIT)   // 128
#define G_KB     32
__global__ __launch_bounds__(128, 1)
void k_gate(const float* __restrict__ hs, const float* __restrict__ gw,
            double* __restrict__ lg) {
  __shared__ float sA[128 * G_KB];   // XOR-swizzled 4-float units
  __shared__ float sB[64 * G_KB];
  const int t = threadIdx.x;
  const int ksBase = blockIdx.x * G_KSEG;
  const int tokBase = blockIdx.y * 128;
  const int tx = t & 7;        // expert octet
  const int ty = t >> 3;       // token octet (0..15)

  double acc[8][8] = {};

  for (int kb = 0; kb < G_KSEG / G_KB; ++kb) {
    const int k0 = ksBase + kb * G_KB;
    // stage A: 128 rows x 32 k, units of 4 floats, swizzle key (row>>3)&7
#pragma unroll
    for (int it = 0; it < 8; ++it) {
      int idx = t + it * 128;
      int row = idx >> 3, u = idx & 7;
      fv4 v = *(const fv4*)(hs + (size_t)(tokBase + row) * HD + k0 + u * 4);
      *(fv4*)&sA[row * 32 + ((u ^ ((row >> 3) & 7)) * 4)] = v;
    }
    // stage B: 64 rows x 32 k
#pragma unroll
    for (int it = 0; it < 4; ++it) {
      int idx = t + it * 128;
      int row = idx >> 3, u = idx & 7;
      fv4 v = *(const fv4*)(gw + (size_t)row * HD + k0 + u * 4);
      *(fv4*)&sB[row * 32 + ((u ^ ((row >> 3) & 7)) * 4)] = v;
    }
    __syncthreads();
#pragma unroll
    for (int k4 = 0; k4 < 8; ++k4) {
      fv4 av[8], bv[8];
#pragma unroll
      for (int i = 0; i < 8; ++i)
        av[i] = *(const fv4*)&sA[(8 * ty + i) * 32 + ((k4 ^ (ty & 7)) * 4)];
#pragma unroll
      for (int j = 0; j < 8; ++j)
        bv[j] = *(const fv4*)&sB[(8 * tx + j) * 32 + ((k4 ^ tx) * 4)];
#pragma unroll
      for (int kk = 0; kk < 4; ++kk) {
        double ad[8], bd[8];
#pragma unroll
        for (int i = 0; i < 8; ++i) ad[i] = (double)av[i][kk];
#pragma unroll
        for (int j = 0; j < 8; ++j) bd[j] = (double)bv[j][kk];
#pragma unroll
        for (int i = 0; i < 8; ++i)
#pragma unroll
          for (int j = 0; j < 8; ++j)
            acc[i][j] = __builtin_fma(ad[i], bd[j], acc[i][j]);
      }
    }
    __syncthreads();
  }
#pragma unroll
  for (int i = 0; i < 8; ++i)
#pragma unroll
    for (int j = 0; j < 8; ++j)
      unsafeAtomicAdd(&lg[(size_t)(tokBase + 8 * ty + i) * NE + 8 * tx + j],
                      acc[i][j]);
}

// ---------- K2: difficulty head GEMM, split-bf16 3-term MFMA ----------
// grid (4 n-chunks, 128 token-tiles) = 512 blocks (2/CU), block 256 (4 waves)
// tile: 128 tokens x 128 cols; wave = 64 tok x 64 col (4x4 16x16 tiles)
// hs (134 MB) fits in L3; 4-fold logical re-read mostly L3-absorbed.
#define D_MT 128
#define D_NT 128
#define D_KB 32
__global__ __launch_bounds__(256, 2)
void k_diff(const float* __restrict__ hs, const float* __restrict__ w1,
            const float* __restrict__ b1, const float* __restrict__ w2,
            float* __restrict__ x2) {
  __shared__ unsigned short sAh[D_MT * D_KB];
  __shared__ unsigned short sAl[D_MT * D_KB];
  __shared__ unsigned short sBh[D_NT * D_KB];
  __shared__ unsigned short sBl[D_NT * D_KB];

  const int t = threadIdx.x;
  const int nBase = blockIdx.x * D_NT;
  const int tokBase = blockIdx.y * D_MT;
  const int w = t >> 6, lane = t & 63, l15 = lane & 15, q = lane >> 4;
  const int waveM = w & 1, waveN = w >> 1;

  f32x4 acc[4][4] = {};

  for (int kb = 0; kb < HD / D_KB; ++kb) {
    const int k0 = kb * D_KB;
    // stage A: 128 rows x 32 k as bf16 hi/lo; 16B units of 8 bf16,
    // swizzle key (row>>2)&3
#pragma unroll
    for (int it = 0; it < 2; ++it) {
      int idx = t + it * 256;
      int row = idx >> 2, u = idx & 3;
      const float* g = hs + (size_t)(tokBase + row) * HD + k0 + u * 8;
      fv4 v0 = *(const fv4*)g;
      fv4 v1 = *(const fv4*)(g + 4);
      union { unsigned short s[8]; uint4 v; } ph, pl;
#pragma unroll
      for (int j = 0; j < 8; ++j) {
        float x = (j < 4) ? v0[j] : v1[j - 4];
        unsigned short h = bf_rne(x);
        ph.s[j] = h;
        pl.s[j] = bf_rne(x - bf_to_f(h));
      }
      int up = u ^ ((row >> 2) & 3);
      *(uint4*)&sAh[row * 32 + up * 8] = ph.v;
      *(uint4*)&sAl[row * 32 + up * 8] = pl.v;
    }
    // stage B: 128 rows x 32 k
#pragma unroll
    for (int it = 0; it < 2; ++it) {
      int idx = t + it * 256;
      int row = idx >> 2, u = idx & 3;
      const float* g = w1 + (size_t)(nBase + row) * HD + k0 + u * 8;
      fv4 v0 = *(const fv4*)g;
      fv4 v1 = *(const fv4*)(g + 4);
      union { unsigned short s[8]; uint4 v; } ph, pl;
#pragma unroll
      for (int j = 0; j < 8; ++j) {
        float x = (j < 4) ? v0[j] : v1[j - 4];
        unsigned short h = bf_rne(x);
        ph.s[j] = h;
        pl.s[j] = bf_rne(x - bf_to_f(h));
      }
      int up = u ^ ((row >> 2) & 3);
      *(uint4*)&sBh[row * 32 + up * 8] = ph.v;
      *(uint4*)&sBl[row * 32 + up * 8] = pl.v;
    }
    __syncthreads();

    bf16x8 bh[4], bl[4];
#pragma unroll
    for (int ct = 0; ct < 4; ++ct) {
      int row = waveN * 64 + ct * 16 + l15;
      int off = row * 32 + ((q ^ ((row >> 2) & 3)) * 8);
      bh[ct] = *(const bf16x8*)&sBh[off];
      bl[ct] = *(const bf16x8*)&sBl[off];
    }
#pragma unroll
    for (int rt = 0; rt < 4; ++rt) {
      int row = waveM * 64 + rt * 16 + l15;
      int off = row * 32 + ((q ^ ((row >> 2) & 3)) * 8);
      bf16x8 ah = *(const bf16x8*)&sAh[off];
      bf16x8 al = *(const bf16x8*)&sAl[off];
#pragma unroll
      for (int ct = 0; ct < 4; ++ct) {
        acc[rt][ct] = __builtin_amdgcn_mfma_f32_16x16x32_bf16(ah, bh[ct], acc[rt][ct], 0, 0, 0);
        acc[rt][ct] = __builtin_amdgcn_mfma_f32_16x16x32_bf16(ah, bl[ct], acc[rt][ct], 0, 0, 0);
        acc[rt][ct] = __builtin_amdgcn_mfma_f32_16x16x32_bf16(al, bh[ct], acc[rt][ct], 0, 0, 0);
      }
    }
    __syncthreads();
  }

  // epilogue: x1 + b1 -> silu -> *w2 -> reduce over this wave's 64 cols
  // -> atomic into x2 (8 contributions/token: 2 col-half waves x 4 n-chunks)
  float b1v[4], w2v[4];
#pragma unroll
  for (int ct = 0; ct < 4; ++ct) {
    int c = nBase + waveN * 64 + ct * 16 + l15;
    b1v[ct] = b1[c];
    w2v[ct] = w2[c];
  }
#pragma unroll
  for (int rt = 0; rt < 4; ++rt) {
#pragma unroll
    for (int i = 0; i < 4; ++i) {
      float s = 0.f;
#pragma unroll
      for (int ct = 0; ct < 4; ++ct) {
        float x1 = acc[rt][ct][i] + b1v[ct];
        float h1 = x1 / (1.f + expf(-x1));   // silu
        s += h1 * w2v[ct];
      }
      s += __shfl_xor(s, 1, 64);
      s += __shfl_xor(s, 2, 64);
      s += __shfl_xor(s, 4, 64);
      s += __shfl_xor(s, 8, 64);
      if (l15 == 0)
        unsafeAtomicAdd(&x2[tokBase + waveM * 64 + rt * 16 + q * 4 + i], s);
    }
  }
}

// ---------- K3: per-token routing (one wave = one token's 64 experts) ----------
__global__ __launch_bounds__(256)
void k_route(const double* __restrict__ lg, const float* __restrict__ x2,
             const float* __restrict__ b2, float* __restrict__ out,
             double* __restrict__ tpe, double* __restrict__ ks_es) {
  const int t = threadIdx.x, wv = t >> 6, e = t & 63;
  const int base = blockIdx.x * 64 + wv * 16;
  const float b2v = b2[0];
  double tacc = 0.0, kacc = 0.0, eacc = 0.0;

  for (int it = 0; it < 16; ++it) {
    const int tok = base + it;
    float my = (float)lg[(size_t)tok * NE + e];
    float xv = x2[tok] + b2v;
    float d = 1.f / (1.f + expf(-xv));
    float kf = 4.f + 8.f * d;
    int ki = (int)rintf(kf);           // round-half-even, matches jnp.round
    ki = min(max(ki, 4), 12);

    int r = 0;  // stable descending rank
#pragma unroll
    for (int s = 1; s < 64; ++s) {
      int src = (e + s) & 63;
      float o = __shfl(my, src, 64);
      r += (o > my || (o == my && src < e)) ? 1 : 0;
    }
    float m = my;
#pragma unroll
    for (int off = 1; off < 64; off <<= 1) m = fmaxf(m, __shfl_xor(m, off, 64));
    float ex = (r < ki) ? expf(my - m) : 0.f;
    float sm = ex;
#pragma unroll
    for (int off = 1; off < 64; off <<= 1) sm += __shfl_xor(sm, off, 64);
    float wgt = ex / sm;
    out[(size_t)tok * NE + e] = wgt;

    tacc += (double)wgt;
    kacc += (double)kf;
    eacc += (double)(d * logf(d + 1e-8f) + (1.f - d) * logf(1.f - d + 1e-8f));
  }
  unsafeAtomicAdd(&tpe[e], tacc);
  if (e == 0) {
    unsafeAtomicAdd(&ks_es[0], kacc);
    unsafeAtomicAdd(&ks_es[1], eacc);
  }
}

// ---------- K4: aux loss ----------
__global__ void k_aux(const double* __restrict__ tpe,
                      const double* __restrict__ ks_es,
                      float* __restrict__ out) {
  const int e = threadIdx.x;  // 64 threads
  double x = tpe[e];
  double s = x;
#pragma unroll
  for (int off = 1; off < 64; off <<= 1) s += __shfl_xor(s, off, 64);
  double mean = s / 64.0;
  double dv = x - mean, v = dv * dv;
#pragma unroll
  for (int off = 1; off < 64; off <<= 1) v += __shfl_xor(v, off, 64);
  double var = v / 63.0;                       // ddof=1
  double avgk = ks_es[0] / (double)NTOK;
  double kp = 8.0 - avgk;
  kp = kp > 0.0 ? kp * kp : 0.0;               // relu(BASE_K-avg_k)^2
  double bal = var / (mean + 1e-8);
  double aux = 0.01 * (kp + bal) + 0.001 * (ks_es[1] / (double)NTOK);
  if (e == 0) out[(size_t)NTOK * NE] = (float)aux;
}

// ---------- launch ----------
extern "C" void kernel_launch(void* const* d_in, const int* in_sizes, int n_in,
                              void* d_out, int out_size, void* d_ws, size_t ws_size,
                              hipStream_t stream) {
  const float* hs = (const float*)d_in[0];
  const float* gw = (const float*)d_in[1];
  const float* w1 = (const float*)d_in[2];
  const float* b1 = (const float*)d_in[3];
  const float* w2 = (const float*)d_in[4];
  const float* b2 = (const float*)d_in[5];
  float* out = (float*)d_out;

  // workspace layout (needs ~8.07 MB)
  char* ws = (char*)d_ws;
  double* lg   = (double*)ws;               // 16384*64*8 = 8,388,608
  float*  x2   = (float*)(ws + 8388608);    // 16384*4    = 65,536
  double* tpe  = (double*)(ws + 8454144);   // 64*8       = 512
  double* ks_es = (double*)(ws + 8454656);  // 2*8        = 16

  const int n16 = 8454672 / 16;
  k_zero<<<1040, 256, 0, stream>>>((uint4*)d_ws, n16);
  k_gate<<<dim3(G_KSPLIT, NTOK / 128), 128, 0, stream>>>(hs, gw, lg);
  k_diff<<<dim3(ND / D_NT, NTOK / D_MT), 256, 0, stream>>>(hs, w1, b1, w2, x2);
  k_route<<<NTOK / 64, 256, 0, stream>>>(lg, x2, b2, out, tpe, ks_es);
  k_aux<<<1, 64, 0, stream>>>(tpe, ks_es, out);
}

// Round 5
// 460.453 us; speedup vs baseline: 5.1499x; 2.7046x over previous
//
#include <hip/hip_runtime.h>
#include <stdint.h>

// Problem constants (match reference)
#define NE   64      // experts
#define HD   2048    // hidden dim
#define ND   512     // difficulty head inner dim
#define NTOK 16384   // B*S = 4*4096

typedef __attribute__((ext_vector_type(4))) float   fv4;
typedef __attribute__((ext_vector_type(8))) short   bf16x8;
typedef __attribute__((ext_vector_type(4))) float   f32x4;

// ---------- helpers ----------
__device__ inline unsigned short bf_rne(float x) {
  unsigned int u = __float_as_uint(x);
  return (unsigned short)((u + 0x7FFFu + ((u >> 16) & 1u)) >> 16);
}
__device__ inline float bf_to_f(unsigned short h) {
  return __uint_as_float((unsigned int)h << 16);
}
// exact 3-way truncation split: x == h + m + l exactly (8+8+8 = 24 mantissa bits)
__device__ inline void split3(float x, unsigned short& h, unsigned short& m,
                              unsigned short& l) {
  unsigned int u = __float_as_uint(x);
  h = (unsigned short)(u >> 16);                       // truncate: exact piece
  float r1 = x - __uint_as_float(u & 0xFFFF0000u);     // exact in fp32
  unsigned int um = __float_as_uint(r1);
  m = (unsigned short)(um >> 16);
  float r2 = r1 - __uint_as_float(um & 0xFFFF0000u);   // exact, <=8 sig bits
  l = bf_rne(r2);                                      // exactly representable
}

// ---------- K0: zero x2/tpe/ks_es ----------
__global__ void k_zero(uint4* __restrict__ p, int n16) {
  uint4 z = {0u, 0u, 0u, 0u};
  for (int i = blockIdx.x * blockDim.x + threadIdx.x; i < n16;
       i += gridDim.x * blockDim.x)
    p[i] = z;
}

// ---------- K0b: w1 fp32 -> bf16 hi/lo planes (rne split, 3-term products) --
__global__ __launch_bounds__(256)
void k_prep(const float* __restrict__ w1, unsigned short* __restrict__ w1h,
            unsigned short* __restrict__ w1l) {
  int i = (blockIdx.x * 256 + threadIdx.x) * 8;
  fv4 v0 = *(const fv4*)(w1 + i);
  fv4 v1 = *(const fv4*)(w1 + i + 4);
  union { unsigned short s[8]; uint4 v; } ph, pl;
#pragma unroll
  for (int j = 0; j < 8; ++j) {
    float x = (j < 4) ? v0[j] : v1[j - 4];
    unsigned short h = bf_rne(x);
    ph.s[j] = h;
    pl.s[j] = bf_rne(x - bf_to_f(h));
  }
  *(uint4*)(w1h + i) = ph.v;
  *(uint4*)(w1l + i) = pl.v;
}

// ---------- K1: gate logits, EXACT-split 6-term bf16 MFMA ----------
// Each fp32 split exactly into 3 bf16 (h,m,l). Products of 8-bit-mantissa
// pieces are exact in fp32; keeping hh+hm+mh+mm+hl+lh drops only ~2^-24-rel
// terms. Accumulation noise (K=1024/split, fp32) ~3e-7 < np sgemm's own
// ~1.3e-6 -> same top-k rank fidelity as the proven fp64 path.
// grid (2 K-splits, 256 token-tiles), block 256 = 4 waves.
// Block tile 64 tok x 64 exp; wave = 32x32 (2x2 16x16 tiles).
// Split-0 partials -> ws, split-1 partials -> d_out (consumed in k_route by
// the same lane that overwrites them). Uses r3-PROVEN bf16 MFMA layout.
__global__ __launch_bounds__(256)
void k_gate(const float* __restrict__ hs, const float* __restrict__ gw,
            float* __restrict__ lg0, float* __restrict__ lg1) {
  __shared__ unsigned short sAh[64 * 32], sAm[64 * 32], sAl[64 * 32];
  __shared__ unsigned short sBh[64 * 32], sBm[64 * 32], sBl[64 * 32];
  const int t = threadIdx.x;
  const int split = blockIdx.x;            // 0 or 1
  const int k0base = split * (HD / 2);
  const int tokBase = blockIdx.y * 64;
  const int w = t >> 6, l = t & 63, l15 = l & 15, q = l >> 4;
  const int waveM = w & 1, waveN = w >> 1;

  f32x4 acc[2][2] = {};

  for (int kb = 0; kb < (HD / 2) / 32; ++kb) {
    const int k0 = k0base + kb * 32;
    // stage A(hs) and B(gw): 64 rows x 32 k each = 256 16B-units = 1/thread.
    // unit index = row*4 + qq = t  (contiguous LDS stores, uniform-bank reads)
    {
      int row = t >> 2, qq = t & 3;
      const float* ga = hs + (size_t)(tokBase + row) * HD + k0 + qq * 8;
      const float* gb = gw + (size_t)row * HD + k0 + qq * 8;
      fv4 a0 = *(const fv4*)ga, a1 = *(const fv4*)(ga + 4);
      fv4 b0 = *(const fv4*)gb, b1_ = *(const fv4*)(gb + 4);
      union { unsigned short s[8]; uint4 v; } xh, xm, xl, yh, ym, yl;
#pragma unroll
      for (int j = 0; j < 8; ++j) {
        float xa = (j < 4) ? a0[j] : a1[j - 4];
        float xb = (j < 4) ? b0[j] : b1_[j - 4];
        split3(xa, xh.s[j], xm.s[j], xl.s[j]);
        split3(xb, yh.s[j], ym.s[j], yl.s[j]);
      }
      *(uint4*)&sAh[t * 8] = xh.v;  *(uint4*)&sAm[t * 8] = xm.v;
      *(uint4*)&sAl[t * 8] = xl.v;  *(uint4*)&sBh[t * 8] = yh.v;
      *(uint4*)&sBm[t * 8] = ym.v;  *(uint4*)&sBl[t * 8] = yl.v;
    }
    __syncthreads();

    bf16x8 ah[2], am[2], al[2], bh[2], bm[2], bl[2];
#pragma unroll
    for (int rt = 0; rt < 2; ++rt) {
      int row = waveM * 32 + rt * 16 + l15;
      int off = (row * 4 + q) * 8;
      ah[rt] = *(const bf16x8*)&sAh[off];
      am[rt] = *(const bf16x8*)&sAm[off];
      al[rt] = *(const bf16x8*)&sAl[off];
    }
#pragma unroll
    for (int ct = 0; ct < 2; ++ct) {
      int row = waveN * 32 + ct * 16 + l15;
      int off = (row * 4 + q) * 8;
      bh[ct] = *(const bf16x8*)&sBh[off];
      bm[ct] = *(const bf16x8*)&sBm[off];
      bl[ct] = *(const bf16x8*)&sBl[off];
    }
#pragma unroll
    for (int rt = 0; rt < 2; ++rt)
#pragma unroll
      for (int ct = 0; ct < 2; ++ct) {
        acc[rt][ct] = __builtin_amdgcn_mfma_f32_16x16x32_bf16(al[rt], bh[ct], acc[rt][ct], 0, 0, 0);
        acc[rt][ct] = __builtin_amdgcn_mfma_f32_16x16x32_bf16(ah[rt], bl[ct], acc[rt][ct], 0, 0, 0);
        acc[rt][ct] = __builtin_amdgcn_mfma_f32_16x16x32_bf16(am[rt], bm[ct], acc[rt][ct], 0, 0, 0);
        acc[rt][ct] = __builtin_amdgcn_mfma_f32_16x16x32_bf16(am[rt], bh[ct], acc[rt][ct], 0, 0, 0);
        acc[rt][ct] = __builtin_amdgcn_mfma_f32_16x16x32_bf16(ah[rt], bm[ct], acc[rt][ct], 0, 0, 0);
        acc[rt][ct] = __builtin_amdgcn_mfma_f32_16x16x32_bf16(ah[rt], bh[ct], acc[rt][ct], 0, 0, 0);
      }
    __syncthreads();
  }

  float* dst = (split == 0) ? lg0 : lg1;
#pragma unroll
  for (int rt = 0; rt < 2; ++rt)
#pragma unroll
    for (int ct = 0; ct < 2; ++ct)
#pragma unroll
      for (int i = 0; i < 4; ++i)
        dst[(size_t)(tokBase + waveM * 32 + rt * 16 + q * 4 + i) * NE +
            waveN * 32 + ct * 16 + l15] = acc[rt][ct][i];
}

// ---------- K2: difficulty head GEMM, split-bf16 3-term MFMA ----------
// grid (4 n-chunks, 128 token-tiles) = 512 blocks, block 256 (4 waves 2x2).
// Block tile 128 tok x 128 col, KB=32. LDS unit = row*4 + q (contiguous
// stores, uniform-bank b128 reads). w1 pre-split planes; hs split inline.
__global__ __launch_bounds__(256)
void k_diff(const float* __restrict__ hs, const unsigned short* __restrict__ w1h,
            const unsigned short* __restrict__ w1l, const float* __restrict__ b1,
            const float* __restrict__ w2, float* __restrict__ x2) {
  __shared__ unsigned short sAh[512 * 8];
  __shared__ unsigned short sAl[512 * 8];
  __shared__ unsigned short sBh[512 * 8];
  __shared__ unsigned short sBl[512 * 8];

  const int t = threadIdx.x;
  const int nBase = blockIdx.x * 128;
  const int tokBase = blockIdx.y * 128;
  const int w = t >> 6, l = t & 63, l15 = l & 15, q = l >> 4;
  const int waveM = w & 1, waveN = w >> 1;

  f32x4 acc[4][4] = {};

  for (int kb = 0; kb < HD / 32; ++kb) {
    const int k0 = kb * 32;
    // A: 128 rows x 4 q-units (unit idx = row*4+qq = u), fp32 -> hi/lo rne.
#pragma unroll
    for (int j = 0; j < 2; ++j) {
      int u = t + j * 256;
      int row = u >> 2, qq = u & 3;
      const float* g = hs + (size_t)(tokBase + row) * HD + k0 + qq * 8;
      fv4 v0 = *(const fv4*)g;
      fv4 v1 = *(const fv4*)(g + 4);
      union { unsigned short s[8]; uint4 v; } ph, pl;
#pragma unroll
      for (int jj = 0; jj < 8; ++jj) {
        float x = (jj < 4) ? v0[jj] : v1[jj - 4];
        unsigned short h = bf_rne(x);
        ph.s[jj] = h;
        pl.s[jj] = bf_rne(x - bf_to_f(h));
      }
      *(uint4*)&sAh[u * 8] = ph.v;
      *(uint4*)&sAl[u * 8] = pl.v;
    }
    // B: 512 units per plane, straight 16B copies.
#pragma unroll
    for (int j2 = 0; j2 < 4; ++j2) {
      int u = t + (j2 & 1) * 256;
      int row = u >> 2, qq = u & 3;
      const unsigned short* src = (j2 < 2) ? w1h : w1l;
      uint4 v = *(const uint4*)(src + (size_t)(nBase + row) * HD + k0 + qq * 8);
      unsigned short* dst = (j2 < 2) ? sBh : sBl;
      *(uint4*)&dst[u * 8] = v;
    }
    __syncthreads();

    bf16x8 bh[4], bl[4];
#pragma unroll
    for (int ct = 0; ct < 4; ++ct) {
      int row = waveN * 64 + ct * 16 + l15;
      bh[ct] = *(const bf16x8*)&sBh[(row * 4 + q) * 8];
      bl[ct] = *(const bf16x8*)&sBl[(row * 4 + q) * 8];
    }
#pragma unroll
    for (int rt = 0; rt < 4; ++rt) {
      int row = waveM * 64 + rt * 16 + l15;
      bf16x8 ah = *(const bf16x8*)&sAh[(row * 4 + q) * 8];
      bf16x8 al = *(const bf16x8*)&sAl[(row * 4 + q) * 8];
#pragma unroll
      for (int ct = 0; ct < 4; ++ct) {
        acc[rt][ct] = __builtin_amdgcn_mfma_f32_16x16x32_bf16(ah, bh[ct], acc[rt][ct], 0, 0, 0);
        acc[rt][ct] = __builtin_amdgcn_mfma_f32_16x16x32_bf16(ah, bl[ct], acc[rt][ct], 0, 0, 0);
        acc[rt][ct] = __builtin_amdgcn_mfma_f32_16x16x32_bf16(al, bh[ct], acc[rt][ct], 0, 0, 0);
      }
    }
    __syncthreads();
  }

  // epilogue: x1 + b1 -> silu -> *w2 -> reduce over wave's 64 cols -> atomic
  float b1v[4], w2v[4];
#pragma unroll
  for (int ct = 0; ct < 4; ++ct) {
    int c = nBase + waveN * 64 + ct * 16 + l15;
    b1v[ct] = b1[c];
    w2v[ct] = w2[c];
  }
#pragma unroll
  for (int rt = 0; rt < 4; ++rt) {
#pragma unroll
    for (int i = 0; i < 4; ++i) {
      float s = 0.f;
#pragma unroll
      for (int ct = 0; ct < 4; ++ct) {
        float x1 = acc[rt][ct][i] + b1v[ct];
        float h1 = x1 / (1.f + expf(-x1));   // silu
        s += h1 * w2v[ct];
      }
      s += __shfl_xor(s, 1, 64);
      s += __shfl_xor(s, 2, 64);
      s += __shfl_xor(s, 4, 64);
      s += __shfl_xor(s, 8, 64);
      if (l15 == 0)
        unsafeAtomicAdd(&x2[tokBase + waveM * 64 + rt * 16 + q * 4 + i], s);
    }
  }
}

// ---------- K3: per-token routing (one wave = one token's 64 experts) -----
// NOTE: `out` holds split-1 gate partials on entry; each lane reads its
// partial BEFORE overwriting that exact element with the routing weight.
__global__ __launch_bounds__(256)
void k_route(const float* __restrict__ lg0, const float* __restrict__ x2,
             const float* __restrict__ b2, float* out,
             double* __restrict__ tpe, double* __restrict__ ks_es) {
  const int t = threadIdx.x, wv = t >> 6, e = t & 63;
  const int base = blockIdx.x * 64 + wv * 16;
  const float b2v = b2[0];
  double tacc = 0.0, kacc = 0.0, eacc = 0.0;

  for (int it = 0; it < 16; ++it) {
    const int tok = base + it;
    const size_t idx = (size_t)tok * NE + e;
    float my = lg0[idx] + out[idx];      // sum K-split partials
    float xv = x2[tok] + b2v;
    float d = 1.f / (1.f + expf(-xv));
    float kf = 4.f + 8.f * d;
    int ki = (int)rintf(kf);             // round-half-even, matches jnp.round
    ki = min(max(ki, 4), 12);

    int r = 0;  // stable descending rank
#pragma unroll
    for (int s = 1; s < 64; ++s) {
      int src = (e + s) & 63;
      float o = __shfl(my, src, 64);
      r += (o > my || (o == my && src < e)) ? 1 : 0;
    }
    float m = my;
#pragma unroll
    for (int off = 1; off < 64; off <<= 1) m = fmaxf(m, __shfl_xor(m, off, 64));
    float ex = (r < ki) ? expf(my - m) : 0.f;
    float sm = ex;
#pragma unroll
    for (int off = 1; off < 64; off <<= 1) sm += __shfl_xor(sm, off, 64);
    float wgt = ex / sm;
    out[idx] = wgt;

    tacc += (double)wgt;
    kacc += (double)kf;
    eacc += (double)(d * logf(d + 1e-8f) + (1.f - d) * logf(1.f - d + 1e-8f));
  }
  unsafeAtomicAdd(&tpe[e], tacc);
  if (e == 0) {
    unsafeAtomicAdd(&ks_es[0], kacc);
    unsafeAtomicAdd(&ks_es[1], eacc);
  }
}

// ---------- K4: aux loss ----------
__global__ void k_aux(const double* __restrict__ tpe,
                      const double* __restrict__ ks_es,
                      float* __restrict__ out) {
  const int e = threadIdx.x;  // 64 threads
  double x = tpe[e];
  double s = x;
#pragma unroll
  for (int off = 1; off < 64; off <<= 1) s += __shfl_xor(s, off, 64);
  double mean = s / 64.0;
  double dv = x - mean, v = dv * dv;
#pragma unroll
  for (int off = 1; off < 64; off <<= 1) v += __shfl_xor(v, off, 64);
  double var = v / 63.0;                       // ddof=1
  double avgk = ks_es[0] / (double)NTOK;
  double kp = 8.0 - avgk;
  kp = kp > 0.0 ? kp * kp : 0.0;               // relu(BASE_K-avg_k)^2
  double bal = var / (mean + 1e-8);
  double aux = 0.01 * (kp + bal) + 0.001 * (ks_es[1] / (double)NTOK);
  if (e == 0) out[(size_t)NTOK * NE] = (float)aux;
}

// ---------- launch ----------
extern "C" void kernel_launch(void* const* d_in, const int* in_sizes, int n_in,
                              void* d_out, int out_size, void* d_ws, size_t ws_size,
                              hipStream_t stream) {
  const float* hs = (const float*)d_in[0];
  const float* gw = (const float*)d_in[1];
  const float* w1 = (const float*)d_in[2];
  const float* b1 = (const float*)d_in[3];
  const float* w2 = (const float*)d_in[4];
  const float* b2 = (const float*)d_in[5];
  float* out = (float*)d_out;
  char* ws = (char*)d_ws;

  // ws layout (exactly the r1-proven 8,454,672 B budget):
  //   [0,       4194304)  split-0 gate partials (fp32)
  //   [4194304, 6291456)  w1 hi plane (bf16)
  //   [6291456, 8388608)  w1 lo plane (bf16)
  //   [8388608, 8454672)  x2 / tpe / ks_es
  // split-1 gate partials live in d_out (4,194,304 B <= out bytes).
  float* lg0 = (float*)ws;
  unsigned short* w1h = (unsigned short*)(ws + 4194304);
  unsigned short* w1l = (unsigned short*)(ws + 6291456);
  char* tail = ws + 8388608;
  float*  x2    = (float*)tail;              // 65,536 B
  double* tpe   = (double*)(tail + 65536);   // 512 B
  double* ks_es = (double*)(tail + 66048);   // 16 B

  k_zero<<<17, 256, 0, stream>>>((uint4*)tail, (65536 + 512 + 16) / 16);
  k_prep<<<(ND * HD) / (256 * 8), 256, 0, stream>>>(w1, w1h, w1l);
  k_gate<<<dim3(2, NTOK / 64), 256, 0, stream>>>(hs, gw, lg0, out);
  k_diff<<<dim3(ND / 128, NTOK / 128), 256, 0, stream>>>(hs, w1h, w1l, b1, w2, x2);
  k_route<<<NTOK / 64, 256, 0, stream>>>(lg0, x2, b2, out, tpe, ks_es);
  k_aux<<<1, 64, 0, stream>>>(tpe, ks_es, out);
}

// Round 6
// 448.936 us; speedup vs baseline: 5.2820x; 1.0257x over previous
//
#include <hip/hip_runtime.h>
#include <stdint.h>

// Problem constants (match reference)
#define NE   64      // experts
#define HD   2048    // hidden dim
#define ND   512     // difficulty head inner dim
#define NTOK 16384   // B*S = 4*4096

typedef __attribute__((ext_vector_type(4))) float   fv4;
typedef __attribute__((ext_vector_type(8))) short   bf16x8;
typedef __attribute__((ext_vector_type(4))) float   f32x4;

// LDS 16B-unit index: row*4 + (q ^ ((row>>2)&3)).
// Frag reads (rows l15-consecutive, fixed q): 16 lanes spread over all 8
// bank-quads 2-way (free, m136). r5's plain row*4+q packed 16 lanes into 2
// quads -> 8.39M conflict cycles measured.
__device__ inline int swz(int row, int q) {
  return row * 4 + (q ^ ((row >> 2) & 3));
}

// ---------- helpers ----------
__device__ inline unsigned short bf_rne(float x) {
  unsigned int u = __float_as_uint(x);
  return (unsigned short)((u + 0x7FFFu + ((u >> 16) & 1u)) >> 16);
}
__device__ inline float bf_to_f(unsigned short h) {
  return __uint_as_float((unsigned int)h << 16);
}
// exact 3-way truncation split: x == h + m + l (8+8+8 mantissa bits)
__device__ inline void split3(float x, unsigned short& h, unsigned short& m,
                              unsigned short& l) {
  unsigned int u = __float_as_uint(x);
  h = (unsigned short)(u >> 16);
  float r1 = x - __uint_as_float(u & 0xFFFF0000u);
  unsigned int um = __float_as_uint(r1);
  m = (unsigned short)(um >> 16);
  float r2 = r1 - __uint_as_float(um & 0xFFFF0000u);
  l = bf_rne(r2);
}

// ---------- K0: zero lg0 + x2/tpe/ks_es (contiguous range) ----------
__global__ void k_zero(uint4* __restrict__ p, int n16) {
  uint4 z = {0u, 0u, 0u, 0u};
  for (int i = blockIdx.x * blockDim.x + threadIdx.x; i < n16;
       i += gridDim.x * blockDim.x)
    p[i] = z;
}

// ---------- K0b: w1 fp32 -> bf16 hi/lo planes ----------
__global__ __launch_bounds__(256)
void k_prep(const float* __restrict__ w1, unsigned short* __restrict__ w1h,
            unsigned short* __restrict__ w1l) {
  int i = (blockIdx.x * 256 + threadIdx.x) * 8;
  fv4 v0 = *(const fv4*)(w1 + i);
  fv4 v1 = *(const fv4*)(w1 + i + 4);
  union { unsigned short s[8]; uint4 v; } ph, pl;
#pragma unroll
  for (int j = 0; j < 8; ++j) {
    float x = (j < 4) ? v0[j] : v1[j - 4];
    unsigned short h = bf_rne(x);
    ph.s[j] = h;
    pl.s[j] = bf_rne(x - bf_to_f(h));
  }
  *(uint4*)(w1h + i) = ph.v;
  *(uint4*)(w1l + i) = pl.v;
}

// ---------- K0c: gw fp32 -> 3 exact bf16 planes (h/m/l) ----------
// Pre-splitting kills the per-token-tile gw re-split (256x redundant in r5).
__global__ __launch_bounds__(256)
void k_prep2(const float* __restrict__ gw, unsigned short* __restrict__ gh,
             unsigned short* __restrict__ gm, unsigned short* __restrict__ gl) {
  int i = (blockIdx.x * 256 + threadIdx.x) * 8;
  fv4 v0 = *(const fv4*)(gw + i);
  fv4 v1 = *(const fv4*)(gw + i + 4);
  union { unsigned short s[8]; uint4 v; } xh, xm, xl;
#pragma unroll
  for (int j = 0; j < 8; ++j) {
    float x = (j < 4) ? v0[j] : v1[j - 4];
    split3(x, xh.s[j], xm.s[j], xl.s[j]);
  }
  *(uint4*)(gh + i) = xh.v;
  *(uint4*)(gm + i) = xm.v;
  *(uint4*)(gl + i) = xl.v;
}

// ---------- K1: gate logits, EXACT-split 6-term bf16 MFMA ----------
// grid (2 K-splits, 256 token-tiles), block 256 = 4 waves.
// Block tile 64 tok x 64 exp; wave = 32x32 (2x2 16x16), r3/r5-PROVEN layout.
// B (gw) staged as pure 16B copies of pre-split planes; A (hs) split3 inline
// (once per element per split). Partials: fp32 atomicAdd into zeroed lg0 —
// exactly 2 commutative contributors/element => bit-identical to r5's p0+p1.
__global__ __launch_bounds__(256)
void k_gate(const float* __restrict__ hs, const unsigned short* __restrict__ gh,
            const unsigned short* __restrict__ gm,
            const unsigned short* __restrict__ gl, float* __restrict__ lg) {
  __shared__ unsigned short sAh[256 * 8], sAm[256 * 8], sAl[256 * 8];
  __shared__ unsigned short sBh[256 * 8], sBm[256 * 8], sBl[256 * 8];
  const int t = threadIdx.x;
  const int k0base = blockIdx.x * (HD / 2);
  const int tokBase = blockIdx.y * 64;
  const int w = t >> 6, l = t & 63, l15 = l & 15, q = l >> 4;
  const int waveM = w & 1, waveN = w >> 1;
  // writer decode: unit s = t stores global (row = s>>2, q = (s&3)^((s>>4)&3))
  const int srow = t >> 2, sq = (t & 3) ^ ((t >> 4) & 3);

  f32x4 acc[2][2] = {};

  for (int kb = 0; kb < 32; ++kb) {
    const int k0 = k0base + kb * 32;
    {
      const float* ga = hs + (size_t)(tokBase + srow) * HD + k0 + sq * 8;
      fv4 a0 = *(const fv4*)ga, a1 = *(const fv4*)(ga + 4);
      union { unsigned short s[8]; uint4 v; } xh, xm, xl;
#pragma unroll
      for (int j = 0; j < 8; ++j) {
        float x = (j < 4) ? a0[j] : a1[j - 4];
        split3(x, xh.s[j], xm.s[j], xl.s[j]);
      }
      *(uint4*)&sAh[t * 8] = xh.v;
      *(uint4*)&sAm[t * 8] = xm.v;
      *(uint4*)&sAl[t * 8] = xl.v;
      const size_t gb = (size_t)srow * HD + k0 + sq * 8;
      *(uint4*)&sBh[t * 8] = *(const uint4*)(gh + gb);
      *(uint4*)&sBm[t * 8] = *(const uint4*)(gm + gb);
      *(uint4*)&sBl[t * 8] = *(const uint4*)(gl + gb);
    }
    __syncthreads();

    bf16x8 ah[2], am[2], al[2], bh[2], bm[2], bl[2];
#pragma unroll
    for (int rt = 0; rt < 2; ++rt) {
      int off = swz(waveM * 32 + rt * 16 + l15, q) * 8;
      ah[rt] = *(const bf16x8*)&sAh[off];
      am[rt] = *(const bf16x8*)&sAm[off];
      al[rt] = *(const bf16x8*)&sAl[off];
    }
#pragma unroll
    for (int ct = 0; ct < 2; ++ct) {
      int off = swz(waveN * 32 + ct * 16 + l15, q) * 8;
      bh[ct] = *(const bf16x8*)&sBh[off];
      bm[ct] = *(const bf16x8*)&sBm[off];
      bl[ct] = *(const bf16x8*)&sBl[off];
    }
#pragma unroll
    for (int rt = 0; rt < 2; ++rt)
#pragma unroll
      for (int ct = 0; ct < 2; ++ct) {
        acc[rt][ct] = __builtin_amdgcn_mfma_f32_16x16x32_bf16(al[rt], bh[ct], acc[rt][ct], 0, 0, 0);
        acc[rt][ct] = __builtin_amdgcn_mfma_f32_16x16x32_bf16(ah[rt], bl[ct], acc[rt][ct], 0, 0, 0);
        acc[rt][ct] = __builtin_amdgcn_mfma_f32_16x16x32_bf16(am[rt], bm[ct], acc[rt][ct], 0, 0, 0);
        acc[rt][ct] = __builtin_amdgcn_mfma_f32_16x16x32_bf16(am[rt], bh[ct], acc[rt][ct], 0, 0, 0);
        acc[rt][ct] = __builtin_amdgcn_mfma_f32_16x16x32_bf16(ah[rt], bm[ct], acc[rt][ct], 0, 0, 0);
        acc[rt][ct] = __builtin_amdgcn_mfma_f32_16x16x32_bf16(ah[rt], bh[ct], acc[rt][ct], 0, 0, 0);
      }
    __syncthreads();
  }

#pragma unroll
  for (int rt = 0; rt < 2; ++rt)
#pragma unroll
    for (int ct = 0; ct < 2; ++ct)
#pragma unroll
      for (int i = 0; i < 4; ++i)
        unsafeAtomicAdd(&lg[(size_t)(tokBase + waveM * 32 + rt * 16 + q * 4 + i) * NE +
                            waveN * 32 + ct * 16 + l15], acc[rt][ct][i]);
}

// ---------- K2: difficulty head GEMM, split-bf16 3-term MFMA ----------
// grid (2 n-chunks, 256 token-tiles) = 512 blocks, block 256 (4 waves).
// Block tile 64 tok x 256 col; wave = 64 tok x 64 col (4x4 16x16 tiles).
// hs split hi/lo inline 2x total (was 4x in r5); w1 pre-split plane copies.
__global__ __launch_bounds__(256)
void k_diff(const float* __restrict__ hs, const unsigned short* __restrict__ w1h,
            const unsigned short* __restrict__ w1l, const float* __restrict__ b1,
            const float* __restrict__ w2, float* __restrict__ x2) {
  __shared__ unsigned short sAh[256 * 8];   // 64 rows x 4 q-units
  __shared__ unsigned short sAl[256 * 8];
  __shared__ unsigned short sBh[1024 * 8];  // 256 cols x 4 q-units
  __shared__ unsigned short sBl[1024 * 8];

  const int t = threadIdx.x;
  const int nBase = blockIdx.x * 256;
  const int tokBase = blockIdx.y * 64;
  const int w = t >> 6, l = t & 63, l15 = l & 15, q = l >> 4;
  const int srow = t >> 2, sq = (t & 3) ^ ((t >> 4) & 3);

  f32x4 acc[4][4] = {};

  for (int kb = 0; kb < HD / 32; ++kb) {
    const int k0 = kb * 32;
    // A: 256 units, 1 per thread, fp32 -> hi/lo rne split
    {
      const float* g = hs + (size_t)(tokBase + srow) * HD + k0 + sq * 8;
      fv4 v0 = *(const fv4*)g, v1 = *(const fv4*)(g + 4);
      union { unsigned short s[8]; uint4 v; } ph, pl;
#pragma unroll
      for (int jj = 0; jj < 8; ++jj) {
        float x = (jj < 4) ? v0[jj] : v1[jj - 4];
        unsigned short h = bf_rne(x);
        ph.s[jj] = h;
        pl.s[jj] = bf_rne(x - bf_to_f(h));
      }
      *(uint4*)&sAh[t * 8] = ph.v;
      *(uint4*)&sAl[t * 8] = pl.v;
    }
    // B: 1024 units per plane, 4 per thread, pure 16B copies
#pragma unroll
    for (int j = 0; j < 4; ++j) {
      int s = t + j * 256;
      int brow = s >> 2, bq = (s & 3) ^ ((s >> 4) & 3);
      const size_t gb = (size_t)(nBase + brow) * HD + k0 + bq * 8;
      *(uint4*)&sBh[s * 8] = *(const uint4*)(w1h + gb);
      *(uint4*)&sBl[s * 8] = *(const uint4*)(w1l + gb);
    }
    __syncthreads();

    bf16x8 bh[4], bl[4];
#pragma unroll
    for (int ct = 0; ct < 4; ++ct) {
      int off = swz(w * 64 + ct * 16 + l15, q) * 8;
      bh[ct] = *(const bf16x8*)&sBh[off];
      bl[ct] = *(const bf16x8*)&sBl[off];
    }
#pragma unroll
    for (int rt = 0; rt < 4; ++rt) {
      int off = swz(rt * 16 + l15, q) * 8;
      bf16x8 ah = *(const bf16x8*)&sAh[off];
      bf16x8 al = *(const bf16x8*)&sAl[off];
#pragma unroll
      for (int ct = 0; ct < 4; ++ct) {
        acc[rt][ct] = __builtin_amdgcn_mfma_f32_16x16x32_bf16(ah, bh[ct], acc[rt][ct], 0, 0, 0);
        acc[rt][ct] = __builtin_amdgcn_mfma_f32_16x16x32_bf16(ah, bl[ct], acc[rt][ct], 0, 0, 0);
        acc[rt][ct] = __builtin_amdgcn_mfma_f32_16x16x32_bf16(al, bh[ct], acc[rt][ct], 0, 0, 0);
      }
    }
    __syncthreads();
  }

  // epilogue: x1 + b1 -> silu -> *w2 -> reduce wave's 64 cols -> atomic x2
  // (8 contributors/token: 4 col-waves x 2 n-chunks)
  float b1v[4], w2v[4];
#pragma unroll
  for (int ct = 0; ct < 4; ++ct) {
    int c = nBase + w * 64 + ct * 16 + l15;
    b1v[ct] = b1[c];
    w2v[ct] = w2[c];
  }
#pragma unroll
  for (int rt = 0; rt < 4; ++rt) {
#pragma unroll
    for (int i = 0; i < 4; ++i) {
      float s = 0.f;
#pragma unroll
      for (int ct = 0; ct < 4; ++ct) {
        float x1 = acc[rt][ct][i] + b1v[ct];
        float h1 = x1 / (1.f + expf(-x1));   // silu
        s += h1 * w2v[ct];
      }
      s += __shfl_xor(s, 1, 64);
      s += __shfl_xor(s, 2, 64);
      s += __shfl_xor(s, 4, 64);
      s += __shfl_xor(s, 8, 64);
      if (l15 == 0)
        unsafeAtomicAdd(&x2[tokBase + rt * 16 + q * 4 + i], s);
    }
  }
}

// ---------- K3: per-token routing (one wave = one token's 64 experts) -----
__global__ __launch_bounds__(256)
void k_route(const float* __restrict__ lg, const float* __restrict__ x2,
             const float* __restrict__ b2, float* __restrict__ out,
             double* __restrict__ tpe, double* __restrict__ ks_es) {
  const int t = threadIdx.x, wv = t >> 6, e = t & 63;
  const int base = blockIdx.x * 64 + wv * 16;
  const float b2v = b2[0];
  double tacc = 0.0, kacc = 0.0, eacc = 0.0;

  for (int it = 0; it < 16; ++it) {
    const int tok = base + it;
    const size_t idx = (size_t)tok * NE + e;
    float my = lg[idx];
    float xv = x2[tok] + b2v;
    float d = 1.f / (1.f + expf(-xv));
    float kf = 4.f + 8.f * d;
    int ki = (int)rintf(kf);             // round-half-even, matches jnp.round
    ki = min(max(ki, 4), 12);

    int r = 0;  // stable descending rank
#pragma unroll
    for (int s = 1; s < 64; ++s) {
      int src = (e + s) & 63;
      float o = __shfl(my, src, 64);
      r += (o > my || (o == my && src < e)) ? 1 : 0;
    }
    float m = my;
#pragma unroll
    for (int off = 1; off < 64; off <<= 1) m = fmaxf(m, __shfl_xor(m, off, 64));
    float ex = (r < ki) ? expf(my - m) : 0.f;
    float sm = ex;
#pragma unroll
    for (int off = 1; off < 64; off <<= 1) sm += __shfl_xor(sm, off, 64);
    float wgt = ex / sm;
    out[idx] = wgt;

    tacc += (double)wgt;
    kacc += (double)kf;
    eacc += (double)(d * logf(d + 1e-8f) + (1.f - d) * logf(1.f - d + 1e-8f));
  }
  unsafeAtomicAdd(&tpe[e], tacc);
  if (e == 0) {
    unsafeAtomicAdd(&ks_es[0], kacc);
    unsafeAtomicAdd(&ks_es[1], eacc);
  }
}

// ---------- K4: aux loss ----------
__global__ void k_aux(const double* __restrict__ tpe,
                      const double* __restrict__ ks_es,
                      float* __restrict__ out) {
  const int e = threadIdx.x;  // 64 threads
  double x = tpe[e];
  double s = x;
#pragma unroll
  for (int off = 1; off < 64; off <<= 1) s += __shfl_xor(s, off, 64);
  double mean = s / 64.0;
  double dv = x - mean, v = dv * dv;
#pragma unroll
  for (int off = 1; off < 64; off <<= 1) v += __shfl_xor(v, off, 64);
  double var = v / 63.0;                       // ddof=1
  double avgk = ks_es[0] / (double)NTOK;
  double kp = 8.0 - avgk;
  kp = kp > 0.0 ? kp * kp : 0.0;               // relu(BASE_K-avg_k)^2
  double bal = var / (mean + 1e-8);
  double aux = 0.01 * (kp + bal) + 0.001 * (ks_es[1] / (double)NTOK);
  if (e == 0) out[(size_t)NTOK * NE] = (float)aux;
}

// ---------- launch ----------
extern "C" void kernel_launch(void* const* d_in, const int* in_sizes, int n_in,
                              void* d_out, int out_size, void* d_ws, size_t ws_size,
                              hipStream_t stream) {
  const float* hs = (const float*)d_in[0];
  const float* gw = (const float*)d_in[1];
  const float* w1 = (const float*)d_in[2];
  const float* b1 = (const float*)d_in[3];
  const float* w2 = (const float*)d_in[4];
  const float* b2 = (const float*)d_in[5];
  float* out = (float*)d_out;
  char* ws = (char*)d_ws;

  // ws layout (exactly the r1-proven 8,454,672 B budget):
  //   [0,       4194304)  gate logits lg (fp32, atomically accumulated)
  //   [4194304, 4260368)  x2 / tpe / ks_es  (zeroed together with lg)
  //   [4260368, 6357520)  w1 hi plane (bf16)
  //   [6357520, 8454672)  w1 lo plane (bf16)
  // gw h/m/l planes (786,432 B) staged in d_out; k_route overwrites d_out
  // afterwards (stream-ordered, every element rewritten).
  float* lg = (float*)ws;
  char* tail = ws + 4194304;
  float*  x2    = (float*)tail;              // 65,536 B
  double* tpe   = (double*)(tail + 65536);   // 512 B
  double* ks_es = (double*)(tail + 66048);   // 16 B
  unsigned short* w1h = (unsigned short*)(ws + 4260368);
  unsigned short* w1l = (unsigned short*)(ws + 6357520);
  unsigned short* gwh = (unsigned short*)d_out;
  unsigned short* gwm = gwh + NE * HD;
  unsigned short* gwl = gwm + NE * HD;

  k_zero<<<1040, 256, 0, stream>>>((uint4*)ws, 4260368 / 16);
  k_prep<<<(ND * HD) / (256 * 8), 256, 0, stream>>>(w1, w1h, w1l);
  k_prep2<<<(NE * HD) / (256 * 8), 256, 0, stream>>>(gw, gwh, gwm, gwl);
  k_gate<<<dim3(2, NTOK / 64), 256, 0, stream>>>(hs, gwh, gwm, gwl, lg);
  k_diff<<<dim3(ND / 256, NTOK / 64), 256, 0, stream>>>(hs, w1h, w1l, b1, w2, x2);
  k_route<<<NTOK / 64, 256, 0, stream>>>(lg, x2, b2, out, tpe, ks_es);
  k_aux<<<1, 64, 0, stream>>>(tpe, ks_es, out);
}